// Round 2
// baseline (524.137 us; speedup 1.0000x reference)
//
#include <hip/hip_runtime.h>

#define N_NODES 50000
#define N_EDGES 800000

// ---------------- CSR build ----------------

__global__ void count_deg_kernel(const int* __restrict__ ei, int* __restrict__ deg, int E) {
    int e = blockIdx.x * blockDim.x + threadIdx.x;
    if (e < E) atomicAdd(&deg[ei[E + e]], 1);   // dst = ei[E + e]
}

__global__ void scan_kernel(const int* __restrict__ deg, int* __restrict__ rowptr, int N, int E) {
    __shared__ int part[1024];
    int tid = threadIdx.x;
    int chunk = (N + 1023) >> 10;
    int start = tid * chunk;
    int end = min(start + chunk, N);
    int s = 0;
    for (int i = start; i < end; ++i) s += deg[i];
    part[tid] = s;
    __syncthreads();
    // Hillis-Steele inclusive scan over 1024 partials
    for (int off = 1; off < 1024; off <<= 1) {
        int v = (tid >= off) ? part[tid - off] : 0;
        __syncthreads();
        part[tid] += v;
        __syncthreads();
    }
    int run = part[tid] - s;   // exclusive prefix for this chunk
    for (int i = start; i < end; ++i) { rowptr[i] = run; run += deg[i]; }
    if (tid == 0) rowptr[N] = E;
}

__global__ void fill_kernel(const int* __restrict__ ei, const int* __restrict__ rowptr,
                            int* __restrict__ cursor, int* __restrict__ elist, int E) {
    int e = blockIdx.x * blockDim.x + threadIdx.x;
    if (e < E) {
        int d = ei[E + e];
        int pos = rowptr[d] + atomicAdd(&cursor[d], 1);
        elist[pos] = ei[e];   // src
    }
}

// ---------------- fused dual GEMM: C0 = A@W0, C1 = A@W1 ----------------
// A [N,K], W [K,64] row-major. 32 rows per block, 256 threads.
// thread: o = t&63 (output col), g = t>>6 (row subgroup of 8).

template<int K>
__global__ __launch_bounds__(256) void gemm_dual_kernel(
        const float* __restrict__ A,
        const float* __restrict__ W0, const float* __restrict__ W1,
        float* __restrict__ C0, float* __restrict__ C1, int N) {
    __shared__ float a_lds[32 * K];
    int t = threadIdx.x;
    int n0 = blockIdx.x * 32;

    const int total4 = 32 * K / 4;
    for (int idx = t; idx < total4; idx += 256) {
        int f = idx * 4;
        int r = f / K, c = f % K;
        float4 v = make_float4(0.f, 0.f, 0.f, 0.f);
        if (n0 + r < N) v = *(const float4*)&A[(size_t)(n0 + r) * K + c];
        *(float4*)&a_lds[f] = v;
    }
    __syncthreads();

    int o = t & 63;
    int g = t >> 6;
    float acc0[8], acc1[8];
#pragma unroll
    for (int i = 0; i < 8; ++i) { acc0[i] = 0.f; acc1[i] = 0.f; }

#pragma unroll 4
    for (int k = 0; k < K; ++k) {
        float w0 = W0[k * 64 + o];
        float w1 = W1[k * 64 + o];
#pragma unroll
        for (int i = 0; i < 8; ++i) {
            float a = a_lds[(g * 8 + i) * K + k];
            acc0[i] = fmaf(a, w0, acc0[i]);
            acc1[i] = fmaf(a, w1, acc1[i]);
        }
    }
#pragma unroll
    for (int i = 0; i < 8; ++i) {
        int n = n0 + g * 8 + i;
        if (n < N) {
            C0[(size_t)n * 64 + o] = acc0[i];
            C1[(size_t)n * 64 + o] = acc1[i];
        }
    }
}

// ---------------- mean-aggregate + bias + residual-proj + relu ----------------
// H[n] = relu( mean_{s in in(n)} P[s] + bias + R[n] );  R may alias H.

__global__ __launch_bounds__(256) void agg_relu_kernel(
        const float* __restrict__ P, const float* __restrict__ R,
        const float* __restrict__ bias,
        const int* __restrict__ rowptr, const int* __restrict__ elist,
        float* __restrict__ H, int N) {
    int t = threadIdx.x;
    int n = blockIdx.x * 16 + (t >> 4);
    int l = t & 15;
    if (n >= N) return;
    int r0 = rowptr[n], r1 = rowptr[n + 1];
    float4 acc = make_float4(0.f, 0.f, 0.f, 0.f);
    for (int p = r0; p < r1; ++p) {
        int s = elist[p];
        float4 v = *(const float4*)&P[(size_t)s * 64 + l * 4];
        acc.x += v.x; acc.y += v.y; acc.z += v.z; acc.w += v.w;
    }
    float inv = 1.0f / fmaxf((float)(r1 - r0), 1.0f);
    float4 b = *(const float4*)&bias[l * 4];
    float4 rr = *(const float4*)&R[(size_t)n * 64 + l * 4];
    float4 h;
    h.x = fmaxf(fmaf(acc.x, inv, b.x + rr.x), 0.f);
    h.y = fmaxf(fmaf(acc.y, inv, b.y + rr.y), 0.f);
    h.z = fmaxf(fmaf(acc.z, inv, b.z + rr.z), 0.f);
    h.w = fmaxf(fmaf(acc.w, inv, b.w + rr.w), 0.f);
    *(float4*)&H[(size_t)n * 64 + l * 4] = h;
}

// ---------------- edge MLP: out = relu([h2[src],h2[dst]] @ Wm1 + bm1) @ Wm2 + bm2 ----
// 64 edges x 64 hidden per block (256 threads); 4x4 register tile per thread.

__global__ __launch_bounds__(256) void edge_mlp_kernel(
        const float* __restrict__ h2, const int* __restrict__ ei,
        const float* __restrict__ Wm1, const float* __restrict__ bm1,
        const float* __restrict__ Wm2, const float* __restrict__ bm2,
        float* __restrict__ out, int E) {
    __shared__ float w_lds[128 * 64];    // Wm1 [k][j]
    __shared__ float rep_lds[128 * 64];  // rep [k][e]  (k<64: src feats, k>=64: dst feats)
    int t = threadIdx.x;

    // stage Wm1 (2048 float4)
#pragma unroll
    for (int i = 0; i < 8; ++i) {
        int idx = t + i * 256;
        ((float4*)w_lds)[idx] = ((const float4*)Wm1)[idx];
    }

    // stage rep: 4 threads per edge (2 halves x 2 k-chunks of 32)
    int e = t & 63;
    int part = t >> 6;
    int ge = blockIdx.x * 64 + e;
    int node = (part < 2) ? ei[ge] : ei[E + ge];
    int kb = (part & 1) * 32;
    int roff = (part >= 2) ? 64 : 0;
    const float4* hrow = (const float4*)&h2[(size_t)node * 64 + kb];
#pragma unroll
    for (int i = 0; i < 8; ++i) {
        float4 v = hrow[i];
        int kr = roff + kb + i * 4;
        rep_lds[(kr + 0) * 64 + e] = v.x;
        rep_lds[(kr + 1) * 64 + e] = v.y;
        rep_lds[(kr + 2) * 64 + e] = v.z;
        rep_lds[(kr + 3) * 64 + e] = v.w;
    }
    __syncthreads();

    int eg = t >> 4;         // 0..15 -> edge group of 4
    int jt = t & 15;         // 0..15 -> hidden group of 4
    int e4 = eg * 4, j4 = jt * 4;

    float acc[4][4];
#pragma unroll
    for (int jj = 0; jj < 4; ++jj) {
        float b = bm1[j4 + jj];
        acc[0][jj] = b; acc[1][jj] = b; acc[2][jj] = b; acc[3][jj] = b;
    }

#pragma unroll 4
    for (int k = 0; k < 128; ++k) {
        float4 r = *(const float4*)&rep_lds[k * 64 + e4];
        float4 w = *(const float4*)&w_lds[k * 64 + j4];
        acc[0][0] = fmaf(r.x, w.x, acc[0][0]);
        acc[0][1] = fmaf(r.x, w.y, acc[0][1]);
        acc[0][2] = fmaf(r.x, w.z, acc[0][2]);
        acc[0][3] = fmaf(r.x, w.w, acc[0][3]);
        acc[1][0] = fmaf(r.y, w.x, acc[1][0]);
        acc[1][1] = fmaf(r.y, w.y, acc[1][1]);
        acc[1][2] = fmaf(r.y, w.z, acc[1][2]);
        acc[1][3] = fmaf(r.y, w.w, acc[1][3]);
        acc[2][0] = fmaf(r.z, w.x, acc[2][0]);
        acc[2][1] = fmaf(r.z, w.y, acc[2][1]);
        acc[2][2] = fmaf(r.z, w.z, acc[2][2]);
        acc[2][3] = fmaf(r.z, w.w, acc[2][3]);
        acc[3][0] = fmaf(r.w, w.x, acc[3][0]);
        acc[3][1] = fmaf(r.w, w.y, acc[3][1]);
        acc[3][2] = fmaf(r.w, w.z, acc[3][2]);
        acc[3][3] = fmaf(r.w, w.w, acc[3][3]);
    }

    // relu + 64->2 projection, partial over this thread's 4 j's
    float w2a[4], w2b[4];
#pragma unroll
    for (int jj = 0; jj < 4; ++jj) {
        w2a[jj] = Wm2[(j4 + jj) * 2 + 0];
        w2b[jj] = Wm2[(j4 + jj) * 2 + 1];
    }
    float po[4][2];
#pragma unroll
    for (int i = 0; i < 4; ++i) {
        float s0 = 0.f, s1 = 0.f;
#pragma unroll
        for (int jj = 0; jj < 4; ++jj) {
            float hv = fmaxf(acc[i][jj], 0.f);
            s0 = fmaf(hv, w2a[jj], s0);
            s1 = fmaf(hv, w2b[jj], s1);
        }
        po[i][0] = s0; po[i][1] = s1;
    }
    // reduce across the 16 j-threads (lane bits 0..3)
#pragma unroll
    for (int off = 8; off >= 1; off >>= 1) {
#pragma unroll
        for (int i = 0; i < 4; ++i) {
            po[i][0] += __shfl_xor(po[i][0], off, 64);
            po[i][1] += __shfl_xor(po[i][1], off, 64);
        }
    }
    if (jt == 0) {
        float b0 = bm2[0], b1 = bm2[1];
#pragma unroll
        for (int i = 0; i < 4; ++i) {
            int geo = blockIdx.x * 64 + e4 + i;
            if (geo < E) {
                float2 o2 = make_float2(po[i][0] + b0, po[i][1] + b1);
                *(float2*)&out[(size_t)geo * 2] = o2;
            }
        }
    }
}

// ---------------- launch ----------------

extern "C" void kernel_launch(void* const* d_in, const int* in_sizes, int n_in,
                              void* d_out, int out_size, void* d_ws, size_t ws_size,
                              hipStream_t stream) {
    const float* x   = (const float*)d_in[0];
    const int*   ei  = (const int*)d_in[1];
    const float* W1l = (const float*)d_in[2];
    const float* b1l = (const float*)d_in[3];
    const float* W1r = (const float*)d_in[4];
    const float* W2l = (const float*)d_in[5];
    const float* b2l = (const float*)d_in[6];
    const float* W2r = (const float*)d_in[7];
    const float* Wm1 = (const float*)d_in[8];
    const float* bm1 = (const float*)d_in[9];
    const float* Wm2 = (const float*)d_in[10];
    const float* bm2 = (const float*)d_in[11];
    float* out = (float*)d_out;

    const int N = N_NODES, E = N_EDGES;

    float* B0 = (float*)d_ws;                    // [N,64]: xl, then p2l
    float* B1 = B0 + (size_t)N * 64;             // [N,64]: p1r, then h1
    float* B2 = B1 + (size_t)N * 64;             // [N,64]: p2r, then h2
    int* deg    = (int*)(B2 + (size_t)N * 64);   // [N]
    int* cursor = deg + N;                       // [N]
    int* rowptr = cursor + N;                    // [N+1]
    int* elist  = rowptr + N + 1;                // [E]

    hipMemsetAsync(deg, 0, sizeof(int) * 2 * N, stream);  // deg + cursor

    count_deg_kernel<<<(E + 255) / 256, 256, 0, stream>>>(ei, deg, E);
    scan_kernel<<<1, 1024, 0, stream>>>(deg, rowptr, N, E);
    fill_kernel<<<(E + 255) / 256, 256, 0, stream>>>(ei, rowptr, cursor, elist, E);

    // conv1: xl = x@W1l (B0), p1r = x@W1r (B1); h1 = relu(mean(xl[src]) + b1l + p1r) -> B1
    gemm_dual_kernel<128><<<(N + 31) / 32, 256, 0, stream>>>(x, W1l, W1r, B0, B1, N);
    agg_relu_kernel<<<(N + 15) / 16, 256, 0, stream>>>(B0, B1, b1l, rowptr, elist, B1, N);

    // conv2: p2l = h1@W2l (B0), p2r = h1@W2r (B2); h2 = relu(mean(p2l[src]) + b2l + p2r) -> B2
    gemm_dual_kernel<64><<<(N + 31) / 32, 256, 0, stream>>>(B1, W2l, W2r, B0, B2, N);
    agg_relu_kernel<<<(N + 15) / 16, 256, 0, stream>>>(B0, B2, b2l, rowptr, elist, B2, N);

    // edge MLP
    edge_mlp_kernel<<<E / 64, 256, 0, stream>>>(B2, ei, Wm1, bm1, Wm2, bm2, out, E);
}

// Round 3
// 378.609 us; speedup vs baseline: 1.3844x; 1.3844x over previous
//
#include <hip/hip_runtime.h>

#define N_NODES 50000
#define N_EDGES 800000

// ---------------- CSR build ----------------

__global__ void count_deg_kernel(const int* __restrict__ ei, int* __restrict__ deg, int E) {
    int e = blockIdx.x * blockDim.x + threadIdx.x;
    if (e < E) atomicAdd(&deg[ei[E + e]], 1);   // dst = ei[E + e]
}

__global__ void scan_kernel(const int* __restrict__ deg, int* __restrict__ rowptr, int N, int E) {
    __shared__ int part[1024];
    int tid = threadIdx.x;
    int chunk = (N + 1023) >> 10;
    int start = tid * chunk;
    int end = min(start + chunk, N);
    int s = 0;
    for (int i = start; i < end; ++i) s += deg[i];
    part[tid] = s;
    __syncthreads();
    for (int off = 1; off < 1024; off <<= 1) {
        int v = (tid >= off) ? part[tid - off] : 0;
        __syncthreads();
        part[tid] += v;
        __syncthreads();
    }
    int run = part[tid] - s;   // exclusive prefix for this chunk
    for (int i = start; i < end; ++i) { rowptr[i] = run; run += deg[i]; }
    if (tid == 0) rowptr[N] = E;
}

__global__ void fill_kernel(const int* __restrict__ ei, const int* __restrict__ rowptr,
                            int* __restrict__ cursor, int* __restrict__ elist, int E) {
    int e = blockIdx.x * blockDim.x + threadIdx.x;
    if (e < E) {
        int d = ei[E + e];
        int pos = rowptr[d] + atomicAdd(&cursor[d], 1);
        elist[pos] = ei[e];   // src
    }
}

// ---------------- fused dual GEMM: C0 = A@W0, C1 = A@W1 ----------------
// A [N,K], W [K,64] row-major. 32 rows per block, 256 threads.
// thread: o = t&63 (output col), g = t>>6 (row subgroup of 8).
// Inner loop reads a_lds as float4 broadcast (all 64 lanes same addr -> no conflict).

template<int K>
__global__ __launch_bounds__(256) void gemm_dual_kernel(
        const float* __restrict__ A,
        const float* __restrict__ W0, const float* __restrict__ W1,
        float* __restrict__ C0, float* __restrict__ C1, int N) {
    __shared__ float a_lds[32 * K];
    int t = threadIdx.x;
    int n0 = blockIdx.x * 32;

    const int total4 = 32 * K / 4;
    for (int idx = t; idx < total4; idx += 256) {
        int f = idx * 4;
        int r = f / K, c = f % K;
        float4 v = make_float4(0.f, 0.f, 0.f, 0.f);
        if (n0 + r < N) v = *(const float4*)&A[(size_t)(n0 + r) * K + c];
        *(float4*)&a_lds[f] = v;
    }
    __syncthreads();

    int o = t & 63;
    int g = t >> 6;
    float acc0[8], acc1[8];
#pragma unroll
    for (int i = 0; i < 8; ++i) { acc0[i] = 0.f; acc1[i] = 0.f; }

#pragma unroll 2
    for (int k4 = 0; k4 < K; k4 += 4) {
        float w00 = W0[(k4 + 0) * 64 + o];
        float w01 = W0[(k4 + 1) * 64 + o];
        float w02 = W0[(k4 + 2) * 64 + o];
        float w03 = W0[(k4 + 3) * 64 + o];
        float w10 = W1[(k4 + 0) * 64 + o];
        float w11 = W1[(k4 + 1) * 64 + o];
        float w12 = W1[(k4 + 2) * 64 + o];
        float w13 = W1[(k4 + 3) * 64 + o];
#pragma unroll
        for (int i = 0; i < 8; ++i) {
            float4 a = *(const float4*)&a_lds[(g * 8 + i) * K + k4];
            acc0[i] = fmaf(a.x, w00, acc0[i]);
            acc0[i] = fmaf(a.y, w01, acc0[i]);
            acc0[i] = fmaf(a.z, w02, acc0[i]);
            acc0[i] = fmaf(a.w, w03, acc0[i]);
            acc1[i] = fmaf(a.x, w10, acc1[i]);
            acc1[i] = fmaf(a.y, w11, acc1[i]);
            acc1[i] = fmaf(a.z, w12, acc1[i]);
            acc1[i] = fmaf(a.w, w13, acc1[i]);
        }
    }
#pragma unroll
    for (int i = 0; i < 8; ++i) {
        int n = n0 + g * 8 + i;
        if (n < N) {
            C0[(size_t)n * 64 + o] = acc0[i];
            C1[(size_t)n * 64 + o] = acc1[i];
        }
    }
}

// ---------------- mean-aggregate + bias + residual-proj + relu ----------------
// H[n] = relu( mean_{s in in(n)} P[s] + bias + R[n] );  R may alias H.
// 16 lanes per node, 2-way unrolled gather for MLP.

__global__ __launch_bounds__(256) void agg_relu_kernel(
        const float* __restrict__ P, const float* __restrict__ R,
        const float* __restrict__ bias,
        const int* __restrict__ rowptr, const int* __restrict__ elist,
        float* __restrict__ H, int N) {
    int t = threadIdx.x;
    int n = blockIdx.x * 16 + (t >> 4);
    int l = t & 15;
    if (n >= N) return;
    int r0 = rowptr[n], r1 = rowptr[n + 1];
    float4 a0 = make_float4(0.f, 0.f, 0.f, 0.f);
    float4 a1 = make_float4(0.f, 0.f, 0.f, 0.f);
    int p = r0;
    for (; p + 2 <= r1; p += 2) {
        int sA = elist[p];
        int sB = elist[p + 1];
        float4 v0 = *(const float4*)&P[(size_t)sA * 64 + l * 4];
        float4 v1 = *(const float4*)&P[(size_t)sB * 64 + l * 4];
        a0.x += v0.x; a0.y += v0.y; a0.z += v0.z; a0.w += v0.w;
        a1.x += v1.x; a1.y += v1.y; a1.z += v1.z; a1.w += v1.w;
    }
    if (p < r1) {
        int sA = elist[p];
        float4 v0 = *(const float4*)&P[(size_t)sA * 64 + l * 4];
        a0.x += v0.x; a0.y += v0.y; a0.z += v0.z; a0.w += v0.w;
    }
    a0.x += a1.x; a0.y += a1.y; a0.z += a1.z; a0.w += a1.w;
    float inv = 1.0f / fmaxf((float)(r1 - r0), 1.0f);
    float4 b = *(const float4*)&bias[l * 4];
    float4 rr = *(const float4*)&R[(size_t)n * 64 + l * 4];
    float4 h;
    h.x = fmaxf(fmaf(a0.x, inv, b.x + rr.x), 0.f);
    h.y = fmaxf(fmaf(a0.y, inv, b.y + rr.y), 0.f);
    h.z = fmaxf(fmaf(a0.z, inv, b.z + rr.z), 0.f);
    h.w = fmaxf(fmaf(a0.w, inv, b.w + rr.w), 0.f);
    *(float4*)&H[(size_t)n * 64 + l * 4] = h;
}

// ---------------- edge output: out[e] = relu(Pa[src] + Pb[dst] + bm1) @ Wm2 + bm2 ----
// One thread per edge. Pa/Pb are the per-node halves of the edge-MLP first layer.

__global__ __launch_bounds__(256) void edge_out_kernel(
        const float* __restrict__ Pa, const float* __restrict__ Pb,
        const int* __restrict__ ei,
        const float* __restrict__ bm1,
        const float* __restrict__ Wm2, const float* __restrict__ bm2,
        float* __restrict__ out, int E) {
    int e = blockIdx.x * 256 + threadIdx.x;
    if (e >= E) return;
    int s = ei[e];
    int d = ei[E + e];
    const float4* pa = (const float4*)&Pa[(size_t)s * 64];
    const float4* pb = (const float4*)&Pb[(size_t)d * 64];
    float s0 = bm2[0], s1 = bm2[1];
#pragma unroll
    for (int i = 0; i < 16; ++i) {
        float4 a = pa[i];
        float4 b = pb[i];
        float4 bb = *(const float4*)&bm1[i * 4];       // uniform -> s_load
        float h0 = fmaxf(a.x + b.x + bb.x, 0.f);
        float h1 = fmaxf(a.y + b.y + bb.y, 0.f);
        float h2 = fmaxf(a.z + b.z + bb.z, 0.f);
        float h3 = fmaxf(a.w + b.w + bb.w, 0.f);
        s0 = fmaf(h0, Wm2[(i * 4 + 0) * 2 + 0], s0);
        s1 = fmaf(h0, Wm2[(i * 4 + 0) * 2 + 1], s1);
        s0 = fmaf(h1, Wm2[(i * 4 + 1) * 2 + 0], s0);
        s1 = fmaf(h1, Wm2[(i * 4 + 1) * 2 + 1], s1);
        s0 = fmaf(h2, Wm2[(i * 4 + 2) * 2 + 0], s0);
        s1 = fmaf(h2, Wm2[(i * 4 + 2) * 2 + 1], s1);
        s0 = fmaf(h3, Wm2[(i * 4 + 3) * 2 + 0], s0);
        s1 = fmaf(h3, Wm2[(i * 4 + 3) * 2 + 1], s1);
    }
    *(float2*)&out[(size_t)e * 2] = make_float2(s0, s1);
}

// ---------------- launch ----------------

extern "C" void kernel_launch(void* const* d_in, const int* in_sizes, int n_in,
                              void* d_out, int out_size, void* d_ws, size_t ws_size,
                              hipStream_t stream) {
    const float* x   = (const float*)d_in[0];
    const int*   ei  = (const int*)d_in[1];
    const float* W1l = (const float*)d_in[2];
    const float* b1l = (const float*)d_in[3];
    const float* W1r = (const float*)d_in[4];
    const float* W2l = (const float*)d_in[5];
    const float* b2l = (const float*)d_in[6];
    const float* W2r = (const float*)d_in[7];
    const float* Wm1 = (const float*)d_in[8];
    const float* bm1 = (const float*)d_in[9];
    const float* Wm2 = (const float*)d_in[10];
    const float* bm2 = (const float*)d_in[11];
    float* out = (float*)d_out;

    const int N = N_NODES, E = N_EDGES;

    float* B0 = (float*)d_ws;                    // xl -> p2l -> Pa
    float* B1 = B0 + (size_t)N * 64;             // p1r -> h1 -> Pb
    float* B2 = B1 + (size_t)N * 64;             // p2r -> h2
    int* deg    = (int*)(B2 + (size_t)N * 64);   // [N]
    int* cursor = deg + N;                       // [N]
    int* rowptr = cursor + N;                    // [N+1]
    int* elist  = rowptr + N + 1;                // [E]

    hipMemsetAsync(deg, 0, sizeof(int) * 2 * N, stream);  // deg + cursor

    count_deg_kernel<<<(E + 255) / 256, 256, 0, stream>>>(ei, deg, E);
    scan_kernel<<<1, 1024, 0, stream>>>(deg, rowptr, N, E);
    fill_kernel<<<(E + 255) / 256, 256, 0, stream>>>(ei, rowptr, cursor, elist, E);

    // conv1: xl = x@W1l (B0), p1r = x@W1r (B1); h1 = relu(mean(xl[src]) + b1l + p1r) -> B1
    gemm_dual_kernel<128><<<(N + 31) / 32, 256, 0, stream>>>(x, W1l, W1r, B0, B1, N);
    agg_relu_kernel<<<(N + 15) / 16, 256, 0, stream>>>(B0, B1, b1l, rowptr, elist, B1, N);

    // conv2: p2l = h1@W2l (B0), p2r = h1@W2r (B2); h2 = relu(mean(p2l[src]) + b2l + p2r) -> B2
    gemm_dual_kernel<64><<<(N + 31) / 32, 256, 0, stream>>>(B1, W2l, W2r, B0, B2, N);
    agg_relu_kernel<<<(N + 15) / 16, 256, 0, stream>>>(B0, B2, b2l, rowptr, elist, B2, N);

    // edge-MLP first layer, split per-node: Pa = h2@Wm1_top (B0), Pb = h2@Wm1_bot (B1)
    gemm_dual_kernel<64><<<(N + 31) / 32, 256, 0, stream>>>(B2, Wm1, Wm1 + 64 * 64, B0, B1, N);

    // per-edge: out = relu(Pa[src] + Pb[dst] + bm1) @ Wm2 + bm2
    edge_out_kernel<<<E / 256, 256, 0, stream>>>(B0, B1, ei, bm1, Wm2, bm2, out, E);
}

// Round 4
// 311.680 us; speedup vs baseline: 1.6816x; 1.2147x over previous
//
#include <hip/hip_runtime.h>

#define N_NODES 50000
#define N_EDGES 800000

// ---------------- bf16 helpers (tables stored bf16, math in fp32) ----------------

__device__ __forceinline__ float bf2f(unsigned short u) {
    return __uint_as_float(((unsigned)u) << 16);
}
__device__ __forceinline__ unsigned short f2bf(float f) {
    unsigned u = __float_as_uint(f);
    u += 0x7FFFu + ((u >> 16) & 1u);   // round-to-nearest-even
    return (unsigned short)(u >> 16);
}
__device__ __forceinline__ void stv(float* p, float v) { *p = v; }
__device__ __forceinline__ void stv(unsigned short* p, float v) { *p = f2bf(v); }

// ---------------- CSR build ----------------

__global__ void count_deg_kernel(const int* __restrict__ ei, int* __restrict__ deg, int E) {
    int e = blockIdx.x * blockDim.x + threadIdx.x;
    if (e < E) atomicAdd(&deg[ei[E + e]], 1);   // dst = ei[E + e]
}

__global__ void scan_kernel(const int* __restrict__ deg, int* __restrict__ rowptr, int N, int E) {
    __shared__ int part[1024];
    int tid = threadIdx.x;
    int chunk = (N + 1023) >> 10;
    int start = tid * chunk;
    int end = min(start + chunk, N);
    int s = 0;
    for (int i = start; i < end; ++i) s += deg[i];
    part[tid] = s;
    __syncthreads();
    for (int off = 1; off < 1024; off <<= 1) {
        int v = (tid >= off) ? part[tid - off] : 0;
        __syncthreads();
        part[tid] += v;
        __syncthreads();
    }
    int run = part[tid] - s;   // exclusive prefix for this chunk
    for (int i = start; i < end; ++i) { rowptr[i] = run; run += deg[i]; }
    if (tid == 0) rowptr[N] = E;
}

__global__ void fill_kernel(const int* __restrict__ ei, const int* __restrict__ rowptr,
                            int* __restrict__ cursor, int* __restrict__ elist, int E) {
    int e = blockIdx.x * blockDim.x + threadIdx.x;
    if (e < E) {
        int d = ei[E + e];
        int pos = rowptr[d] + atomicAdd(&cursor[d], 1);
        elist[pos] = ei[e];   // src
    }
}

// ---------------- fused dual GEMM: C0 = A@W0, C1 = A@W1 ----------------
// A [N,K] fp32, W [K,64] fp32. Outputs templated: fp32 or bf16 (gather tables).

template<int K, typename T0, typename T1>
__global__ __launch_bounds__(256) void gemm_dual_kernel(
        const float* __restrict__ A,
        const float* __restrict__ W0, const float* __restrict__ W1,
        T0* __restrict__ C0, T1* __restrict__ C1, int N) {
    __shared__ float a_lds[32 * K];
    int t = threadIdx.x;
    int n0 = blockIdx.x * 32;

    const int total4 = 32 * K / 4;
    for (int idx = t; idx < total4; idx += 256) {
        int f = idx * 4;
        int r = f / K, c = f % K;
        float4 v = make_float4(0.f, 0.f, 0.f, 0.f);
        if (n0 + r < N) v = *(const float4*)&A[(size_t)(n0 + r) * K + c];
        *(float4*)&a_lds[f] = v;
    }
    __syncthreads();

    int o = t & 63;
    int g = t >> 6;
    float acc0[8], acc1[8];
#pragma unroll
    for (int i = 0; i < 8; ++i) { acc0[i] = 0.f; acc1[i] = 0.f; }

#pragma unroll 2
    for (int k4 = 0; k4 < K; k4 += 4) {
        float w00 = W0[(k4 + 0) * 64 + o];
        float w01 = W0[(k4 + 1) * 64 + o];
        float w02 = W0[(k4 + 2) * 64 + o];
        float w03 = W0[(k4 + 3) * 64 + o];
        float w10 = W1[(k4 + 0) * 64 + o];
        float w11 = W1[(k4 + 1) * 64 + o];
        float w12 = W1[(k4 + 2) * 64 + o];
        float w13 = W1[(k4 + 3) * 64 + o];
#pragma unroll
        for (int i = 0; i < 8; ++i) {
            float4 a = *(const float4*)&a_lds[(g * 8 + i) * K + k4];
            acc0[i] = fmaf(a.x, w00, acc0[i]);
            acc0[i] = fmaf(a.y, w01, acc0[i]);
            acc0[i] = fmaf(a.z, w02, acc0[i]);
            acc0[i] = fmaf(a.w, w03, acc0[i]);
            acc1[i] = fmaf(a.x, w10, acc1[i]);
            acc1[i] = fmaf(a.y, w11, acc1[i]);
            acc1[i] = fmaf(a.z, w12, acc1[i]);
            acc1[i] = fmaf(a.w, w13, acc1[i]);
        }
    }
#pragma unroll
    for (int i = 0; i < 8; ++i) {
        int n = n0 + g * 8 + i;
        if (n < N) {
            stv(&C0[(size_t)n * 64 + o], acc0[i]);
            stv(&C1[(size_t)n * 64 + o], acc1[i]);
        }
    }
}

// ---------------- mean-aggregate + bias + residual + relu ----------------
// H[n] = relu( mean_{s in in(n)} P[s] + bias + R[n] );  P is a bf16 table.
// 16 lanes per node: one wave instruction reads a full 128B row, coalesced.

__global__ __launch_bounds__(256) void agg_relu_kernel(
        const unsigned short* __restrict__ P, const float* __restrict__ R,
        const float* __restrict__ bias,
        const int* __restrict__ rowptr, const int* __restrict__ elist,
        float* __restrict__ H, int N) {
    int t = threadIdx.x;
    int n = blockIdx.x * 16 + (t >> 4);
    int l = t & 15;
    if (n >= N) return;
    int r0 = rowptr[n], r1 = rowptr[n + 1];
    float4 a0 = make_float4(0.f, 0.f, 0.f, 0.f);
    float4 a1 = make_float4(0.f, 0.f, 0.f, 0.f);
    int p = r0;
    for (; p + 2 <= r1; p += 2) {
        int sA = elist[p];
        int sB = elist[p + 1];
        ushort4 v0 = *(const ushort4*)&P[(size_t)sA * 64 + l * 4];
        ushort4 v1 = *(const ushort4*)&P[(size_t)sB * 64 + l * 4];
        a0.x += bf2f(v0.x); a0.y += bf2f(v0.y); a0.z += bf2f(v0.z); a0.w += bf2f(v0.w);
        a1.x += bf2f(v1.x); a1.y += bf2f(v1.y); a1.z += bf2f(v1.z); a1.w += bf2f(v1.w);
    }
    if (p < r1) {
        int sA = elist[p];
        ushort4 v0 = *(const ushort4*)&P[(size_t)sA * 64 + l * 4];
        a0.x += bf2f(v0.x); a0.y += bf2f(v0.y); a0.z += bf2f(v0.z); a0.w += bf2f(v0.w);
    }
    a0.x += a1.x; a0.y += a1.y; a0.z += a1.z; a0.w += a1.w;
    float inv = 1.0f / fmaxf((float)(r1 - r0), 1.0f);
    float4 b = *(const float4*)&bias[l * 4];
    float4 rr = *(const float4*)&R[(size_t)n * 64 + l * 4];
    float4 h;
    h.x = fmaxf(fmaf(a0.x, inv, b.x + rr.x), 0.f);
    h.y = fmaxf(fmaf(a0.y, inv, b.y + rr.y), 0.f);
    h.z = fmaxf(fmaf(a0.z, inv, b.z + rr.z), 0.f);
    h.w = fmaxf(fmaf(a0.w, inv, b.w + rr.w), 0.f);
    *(float4*)&H[(size_t)n * 64 + l * 4] = h;
}

// ---------------- edge output: out[e] = relu(Pa[src] + Pb[dst] + bm1) @ Wm2 + bm2 ----
// 16 lanes per edge (coalesced 128B bf16 row reads), 4 edges per thread,
// 16-wide shfl_xor reduction for the 64->2 projection.

__global__ __launch_bounds__(256) void edge_out_kernel(
        const unsigned short* __restrict__ Pa, const unsigned short* __restrict__ Pb,
        const int* __restrict__ ei,
        const float* __restrict__ bm1,
        const float* __restrict__ Wm2, const float* __restrict__ bm2,
        float* __restrict__ out, int E) {
    int t = threadIdx.x;
    int l = t & 15;
    int eg = t >> 4;
    int base = blockIdx.x * 64 + eg;

    float4 bb  = *(const float4*)&bm1[l * 4];
    float4 w01 = *(const float4*)&Wm2[l * 8];      // w[l4+0][0..1], w[l4+1][0..1]
    float4 w23 = *(const float4*)&Wm2[l * 8 + 4];  // w[l4+2][0..1], w[l4+3][0..1]
    float ob0 = bm2[0], ob1 = bm2[1];

#pragma unroll
    for (int it = 0; it < 4; ++it) {
        int e = base + it * 16;
        int s = ei[e];
        int d = ei[E + e];
        ushort4 ua = *(const ushort4*)&Pa[(size_t)s * 64 + l * 4];
        ushort4 ub = *(const ushort4*)&Pb[(size_t)d * 64 + l * 4];
        float h0 = fmaxf(bf2f(ua.x) + bf2f(ub.x) + bb.x, 0.f);
        float h1 = fmaxf(bf2f(ua.y) + bf2f(ub.y) + bb.y, 0.f);
        float h2 = fmaxf(bf2f(ua.z) + bf2f(ub.z) + bb.z, 0.f);
        float h3 = fmaxf(bf2f(ua.w) + bf2f(ub.w) + bb.w, 0.f);
        float s0 = h0 * w01.x + h1 * w01.z + h2 * w23.x + h3 * w23.z;
        float s1 = h0 * w01.y + h1 * w01.w + h2 * w23.y + h3 * w23.w;
#pragma unroll
        for (int off = 8; off >= 1; off >>= 1) {
            s0 += __shfl_xor(s0, off, 64);
            s1 += __shfl_xor(s1, off, 64);
        }
        if (l == 0) {
            *(float2*)&out[(size_t)e * 2] = make_float2(s0 + ob0, s1 + ob1);
        }
    }
}

// ---------------- launch ----------------

extern "C" void kernel_launch(void* const* d_in, const int* in_sizes, int n_in,
                              void* d_out, int out_size, void* d_ws, size_t ws_size,
                              hipStream_t stream) {
    const float* x   = (const float*)d_in[0];
    const int*   ei  = (const int*)d_in[1];
    const float* W1l = (const float*)d_in[2];
    const float* b1l = (const float*)d_in[3];
    const float* W1r = (const float*)d_in[4];
    const float* W2l = (const float*)d_in[5];
    const float* b2l = (const float*)d_in[6];
    const float* W2r = (const float*)d_in[7];
    const float* Wm1 = (const float*)d_in[8];
    const float* bm1 = (const float*)d_in[9];
    const float* Wm2 = (const float*)d_in[10];
    const float* bm2 = (const float*)d_in[11];
    float* out = (float*)d_out;

    const int N = N_NODES, E = N_EDGES;

    // B0: bf16 table (xl -> p2l -> Pa), B1: fp32 p1r/h1 then bf16 Pb, B2: fp32 p2r/h2
    float* B0 = (float*)d_ws;                    // 12.8 MB slot
    float* B1 = B0 + (size_t)N * 64;             // 12.8 MB slot
    float* B2 = B1 + (size_t)N * 64;             // 12.8 MB slot
    int* deg    = (int*)(B2 + (size_t)N * 64);   // [N]
    int* cursor = deg + N;                       // [N]
    int* rowptr = cursor + N;                    // [N+1]
    int* elist  = rowptr + N + 1;                // [E]

    unsigned short* B0h = (unsigned short*)B0;
    unsigned short* B1h = (unsigned short*)B1;

    hipMemsetAsync(deg, 0, sizeof(int) * 2 * N, stream);  // deg + cursor

    count_deg_kernel<<<(E + 255) / 256, 256, 0, stream>>>(ei, deg, E);
    scan_kernel<<<1, 1024, 0, stream>>>(deg, rowptr, N, E);
    fill_kernel<<<(E + 255) / 256, 256, 0, stream>>>(ei, rowptr, cursor, elist, E);

    // conv1: xl = x@W1l (B0, bf16), p1r = x@W1r (B1, fp32)
    gemm_dual_kernel<128><<<(N + 31) / 32, 256, 0, stream>>>(x, W1l, W1r, B0h, B1, N);
    // h1 = relu(mean(xl[src]) + b1l + p1r) -> B1 (fp32)
    agg_relu_kernel<<<(N + 15) / 16, 256, 0, stream>>>(B0h, B1, b1l, rowptr, elist, B1, N);

    // conv2: p2l = h1@W2l (B0, bf16), p2r = h1@W2r (B2, fp32)
    gemm_dual_kernel<64><<<(N + 31) / 32, 256, 0, stream>>>(B1, W2l, W2r, B0h, B2, N);
    // h2 = relu(mean(p2l[src]) + b2l + p2r) -> B2 (fp32)
    agg_relu_kernel<<<(N + 15) / 16, 256, 0, stream>>>(B0h, B2, b2l, rowptr, elist, B2, N);

    // edge-MLP first layer, per-node halves: Pa = h2@Wm1_top (B0, bf16), Pb = h2@Wm1_bot (B1, bf16)
    gemm_dual_kernel<64><<<(N + 31) / 32, 256, 0, stream>>>(B2, Wm1, Wm1 + 64 * 64, B0h, B1h, N);

    // per-edge: out = relu(Pa[src] + Pb[dst] + bm1) @ Wm2 + bm2
    edge_out_kernel<<<E / 64, 256, 0, stream>>>(B0h, B1h, ei, bm1, Wm2, bm2, out, E);
}

// Round 5
// 254.848 us; speedup vs baseline: 2.0567x; 1.2230x over previous
//
#include <hip/hip_runtime.h>

#define N_NODES 50000
#define N_EDGES 800000

// ---------------- bf16 helpers (tables stored bf16, math in fp32) ----------------

__device__ __forceinline__ float bf2f(unsigned short u) {
    return __uint_as_float(((unsigned)u) << 16);
}
__device__ __forceinline__ unsigned short f2bf(float f) {
    unsigned u = __float_as_uint(f);
    u += 0x7FFFu + ((u >> 16) & 1u);   // round-to-nearest-even
    return (unsigned short)(u >> 16);
}
__device__ __forceinline__ void stv(float* p, float v) { *p = v; }
__device__ __forceinline__ void stv(unsigned short* p, float v) { *p = f2bf(v); }

// ---------------- CSR build ----------------

__global__ void count_deg_kernel(const int* __restrict__ ei, int* __restrict__ deg, int E) {
    int e = blockIdx.x * blockDim.x + threadIdx.x;
    if (e < E) atomicAdd(&deg[ei[E + e]], 1);   // dst = ei[E + e]
}

// two-level scan: (1) per-block sums, (2) scan block sums, (3) per-block scan + offset

__global__ __launch_bounds__(256) void block_sum_kernel(
        const int* __restrict__ deg, int* __restrict__ bsum, int N) {
    __shared__ int lds[256];
    int tid = threadIdx.x;
    int idx = blockIdx.x * 256 + tid;
    lds[tid] = (idx < N) ? deg[idx] : 0;
    __syncthreads();
#pragma unroll
    for (int off = 128; off >= 1; off >>= 1) {
        if (tid < off) lds[tid] += lds[tid + off];
        __syncthreads();
    }
    if (tid == 0) bsum[blockIdx.x] = lds[0];
}

__global__ __launch_bounds__(256) void scan_bsums_kernel(
        const int* __restrict__ bsum, int* __restrict__ bofs, int NB) {
    __shared__ int lds[256];
    int tid = threadIdx.x;
    int v = (tid < NB) ? bsum[tid] : 0;
    lds[tid] = v;
    __syncthreads();
#pragma unroll
    for (int off = 1; off < 256; off <<= 1) {
        int u = (tid >= off) ? lds[tid - off] : 0;
        __syncthreads();
        lds[tid] += u;
        __syncthreads();
    }
    if (tid < NB) bofs[tid] = lds[tid] - v;   // exclusive
}

__global__ __launch_bounds__(256) void rowptr_kernel(
        const int* __restrict__ deg, const int* __restrict__ bofs,
        int* __restrict__ rowptr, int N) {
    __shared__ int lds[256];
    int tid = threadIdx.x;
    int idx = blockIdx.x * 256 + tid;
    int v = (idx < N) ? deg[idx] : 0;
    lds[tid] = v;
    __syncthreads();
#pragma unroll
    for (int off = 1; off < 256; off <<= 1) {
        int u = (tid >= off) ? lds[tid - off] : 0;
        __syncthreads();
        lds[tid] += u;
        __syncthreads();
    }
    if (idx <= N) rowptr[idx] = bofs[blockIdx.x] + lds[tid] - v;   // exclusive + offset
}

__global__ void fill_kernel(const int* __restrict__ ei, const int* __restrict__ rowptr,
                            int* __restrict__ cursor, int* __restrict__ elist, int E) {
    int e = blockIdx.x * blockDim.x + threadIdx.x;
    if (e < E) {
        int d = ei[E + e];
        int pos = rowptr[d] + atomicAdd(&cursor[d], 1);
        elist[pos] = ei[e];   // src
    }
}

// ---------------- fused dual GEMM: C0 = A@W0, C1 = A@W1 ----------------
// A [N,K] fp32, W [K,64] fp32. Outputs templated: fp32 or bf16 (gather tables).

template<int K, typename T0, typename T1>
__global__ __launch_bounds__(256) void gemm_dual_kernel(
        const float* __restrict__ A,
        const float* __restrict__ W0, const float* __restrict__ W1,
        T0* __restrict__ C0, T1* __restrict__ C1, int N) {
    __shared__ float a_lds[32 * K];
    int t = threadIdx.x;
    int n0 = blockIdx.x * 32;

    const int total4 = 32 * K / 4;
    for (int idx = t; idx < total4; idx += 256) {
        int f = idx * 4;
        int r = f / K, c = f % K;
        float4 v = make_float4(0.f, 0.f, 0.f, 0.f);
        if (n0 + r < N) v = *(const float4*)&A[(size_t)(n0 + r) * K + c];
        *(float4*)&a_lds[f] = v;
    }
    __syncthreads();

    int o = t & 63;
    int g = t >> 6;
    float acc0[8], acc1[8];
#pragma unroll
    for (int i = 0; i < 8; ++i) { acc0[i] = 0.f; acc1[i] = 0.f; }

#pragma unroll 2
    for (int k4 = 0; k4 < K; k4 += 4) {
        float w00 = W0[(k4 + 0) * 64 + o];
        float w01 = W0[(k4 + 1) * 64 + o];
        float w02 = W0[(k4 + 2) * 64 + o];
        float w03 = W0[(k4 + 3) * 64 + o];
        float w10 = W1[(k4 + 0) * 64 + o];
        float w11 = W1[(k4 + 1) * 64 + o];
        float w12 = W1[(k4 + 2) * 64 + o];
        float w13 = W1[(k4 + 3) * 64 + o];
#pragma unroll
        for (int i = 0; i < 8; ++i) {
            float4 a = *(const float4*)&a_lds[(g * 8 + i) * K + k4];
            acc0[i] = fmaf(a.x, w00, acc0[i]);
            acc0[i] = fmaf(a.y, w01, acc0[i]);
            acc0[i] = fmaf(a.z, w02, acc0[i]);
            acc0[i] = fmaf(a.w, w03, acc0[i]);
            acc1[i] = fmaf(a.x, w10, acc1[i]);
            acc1[i] = fmaf(a.y, w11, acc1[i]);
            acc1[i] = fmaf(a.z, w12, acc1[i]);
            acc1[i] = fmaf(a.w, w13, acc1[i]);
        }
    }
#pragma unroll
    for (int i = 0; i < 8; ++i) {
        int n = n0 + g * 8 + i;
        if (n < N) {
            stv(&C0[(size_t)n * 64 + o], acc0[i]);
            stv(&C1[(size_t)n * 64 + o], acc1[i]);
        }
    }
}

// ---------------- mean-aggregate + bias + residual + relu ----------------
// H[n] = relu( mean_{s in in(n)} P[s] + bias + R[n] );  P is a bf16 table.
// 16 lanes per node: one wave instruction reads a full 128B row, coalesced.

__global__ __launch_bounds__(256) void agg_relu_kernel(
        const unsigned short* __restrict__ P, const float* __restrict__ R,
        const float* __restrict__ bias,
        const int* __restrict__ rowptr, const int* __restrict__ elist,
        float* __restrict__ H, int N) {
    int t = threadIdx.x;
    int n = blockIdx.x * 16 + (t >> 4);
    int l = t & 15;
    if (n >= N) return;
    int r0 = rowptr[n], r1 = rowptr[n + 1];
    float4 a0 = make_float4(0.f, 0.f, 0.f, 0.f);
    float4 a1 = make_float4(0.f, 0.f, 0.f, 0.f);
    int p = r0;
    for (; p + 2 <= r1; p += 2) {
        int sA = elist[p];
        int sB = elist[p + 1];
        ushort4 v0 = *(const ushort4*)&P[(size_t)sA * 64 + l * 4];
        ushort4 v1 = *(const ushort4*)&P[(size_t)sB * 64 + l * 4];
        a0.x += bf2f(v0.x); a0.y += bf2f(v0.y); a0.z += bf2f(v0.z); a0.w += bf2f(v0.w);
        a1.x += bf2f(v1.x); a1.y += bf2f(v1.y); a1.z += bf2f(v1.z); a1.w += bf2f(v1.w);
    }
    if (p < r1) {
        int sA = elist[p];
        ushort4 v0 = *(const ushort4*)&P[(size_t)sA * 64 + l * 4];
        a0.x += bf2f(v0.x); a0.y += bf2f(v0.y); a0.z += bf2f(v0.z); a0.w += bf2f(v0.w);
    }
    a0.x += a1.x; a0.y += a1.y; a0.z += a1.z; a0.w += a1.w;
    float inv = 1.0f / fmaxf((float)(r1 - r0), 1.0f);
    float4 b = *(const float4*)&bias[l * 4];
    float4 rr = *(const float4*)&R[(size_t)n * 64 + l * 4];
    float4 h;
    h.x = fmaxf(fmaf(a0.x, inv, b.x + rr.x), 0.f);
    h.y = fmaxf(fmaf(a0.y, inv, b.y + rr.y), 0.f);
    h.z = fmaxf(fmaf(a0.z, inv, b.z + rr.z), 0.f);
    h.w = fmaxf(fmaf(a0.w, inv, b.w + rr.w), 0.f);
    *(float4*)&H[(size_t)n * 64 + l * 4] = h;
}

// ---------------- edge output: out[e] = relu(Pa[src] + Pb[dst] + bm1) @ Wm2 + bm2 ----
// 16 lanes per edge (coalesced 128B bf16 row reads), 4 edges per thread,
// 16-wide shfl_xor reduction for the 64->2 projection.

__global__ __launch_bounds__(256) void edge_out_kernel(
        const unsigned short* __restrict__ Pa, const unsigned short* __restrict__ Pb,
        const int* __restrict__ ei,
        const float* __restrict__ bm1,
        const float* __restrict__ Wm2, const float* __restrict__ bm2,
        float* __restrict__ out, int E) {
    int t = threadIdx.x;
    int l = t & 15;
    int eg = t >> 4;
    int base = blockIdx.x * 64 + eg;

    float4 bb  = *(const float4*)&bm1[l * 4];
    float4 w01 = *(const float4*)&Wm2[l * 8];      // w[l4+0][0..1], w[l4+1][0..1]
    float4 w23 = *(const float4*)&Wm2[l * 8 + 4];  // w[l4+2][0..1], w[l4+3][0..1]
    float ob0 = bm2[0], ob1 = bm2[1];

#pragma unroll
    for (int it = 0; it < 4; ++it) {
        int e = base + it * 16;
        int s = ei[e];
        int d = ei[E + e];
        ushort4 ua = *(const ushort4*)&Pa[(size_t)s * 64 + l * 4];
        ushort4 ub = *(const ushort4*)&Pb[(size_t)d * 64 + l * 4];
        float h0 = fmaxf(bf2f(ua.x) + bf2f(ub.x) + bb.x, 0.f);
        float h1 = fmaxf(bf2f(ua.y) + bf2f(ub.y) + bb.y, 0.f);
        float h2 = fmaxf(bf2f(ua.z) + bf2f(ub.z) + bb.z, 0.f);
        float h3 = fmaxf(bf2f(ua.w) + bf2f(ub.w) + bb.w, 0.f);
        float s0 = h0 * w01.x + h1 * w01.z + h2 * w23.x + h3 * w23.z;
        float s1 = h0 * w01.y + h1 * w01.w + h2 * w23.y + h3 * w23.w;
#pragma unroll
        for (int off = 8; off >= 1; off >>= 1) {
            s0 += __shfl_xor(s0, off, 64);
            s1 += __shfl_xor(s1, off, 64);
        }
        if (l == 0) {
            *(float2*)&out[(size_t)e * 2] = make_float2(s0 + ob0, s1 + ob1);
        }
    }
}

// ---------------- launch ----------------

extern "C" void kernel_launch(void* const* d_in, const int* in_sizes, int n_in,
                              void* d_out, int out_size, void* d_ws, size_t ws_size,
                              hipStream_t stream) {
    const float* x   = (const float*)d_in[0];
    const int*   ei  = (const int*)d_in[1];
    const float* W1l = (const float*)d_in[2];
    const float* b1l = (const float*)d_in[3];
    const float* W1r = (const float*)d_in[4];
    const float* W2l = (const float*)d_in[5];
    const float* b2l = (const float*)d_in[6];
    const float* W2r = (const float*)d_in[7];
    const float* Wm1 = (const float*)d_in[8];
    const float* bm1 = (const float*)d_in[9];
    const float* Wm2 = (const float*)d_in[10];
    const float* bm2 = (const float*)d_in[11];
    float* out = (float*)d_out;

    const int N = N_NODES, E = N_EDGES;
    const int NB = (N + 255) / 256;   // 196 scan blocks

    // B0: bf16 table (xl -> p2l -> Pa), B1: fp32 p1r/h1 then bf16 Pb, B2: fp32 p2r/h2
    float* B0 = (float*)d_ws;                    // 12.8 MB slot
    float* B1 = B0 + (size_t)N * 64;             // 12.8 MB slot
    float* B2 = B1 + (size_t)N * 64;             // 12.8 MB slot
    int* deg    = (int*)(B2 + (size_t)N * 64);   // [N]
    int* cursor = deg + N;                       // [N]
    int* rowptr = cursor + N;                    // [N+1]
    int* elist  = rowptr + N + 1;                // [E]
    int* bsum   = elist + E;                     // [NB]
    int* bofs   = bsum + NB;                     // [NB]

    unsigned short* B0h = (unsigned short*)B0;
    unsigned short* B1h = (unsigned short*)B1;

    hipMemsetAsync(deg, 0, sizeof(int) * 2 * N, stream);  // deg + cursor

    count_deg_kernel<<<(E + 255) / 256, 256, 0, stream>>>(ei, deg, E);
    block_sum_kernel<<<NB, 256, 0, stream>>>(deg, bsum, N);
    scan_bsums_kernel<<<1, 256, 0, stream>>>(bsum, bofs, NB);
    rowptr_kernel<<<NB, 256, 0, stream>>>(deg, bofs, rowptr, N);
    fill_kernel<<<(E + 255) / 256, 256, 0, stream>>>(ei, rowptr, cursor, elist, E);

    // conv1: xl = x@W1l (B0, bf16), p1r = x@W1r (B1, fp32)
    gemm_dual_kernel<128><<<(N + 31) / 32, 256, 0, stream>>>(x, W1l, W1r, B0h, B1, N);
    // h1 = relu(mean(xl[src]) + b1l + p1r) -> B1 (fp32)
    agg_relu_kernel<<<(N + 15) / 16, 256, 0, stream>>>(B0h, B1, b1l, rowptr, elist, B1, N);

    // conv2: p2l = h1@W2l (B0, bf16), p2r = h1@W2r (B2, fp32)
    gemm_dual_kernel<64><<<(N + 31) / 32, 256, 0, stream>>>(B1, W2l, W2r, B0h, B2, N);
    // h2 = relu(mean(p2l[src]) + b2l + p2r) -> B2 (fp32)
    agg_relu_kernel<<<(N + 15) / 16, 256, 0, stream>>>(B0h, B2, b2l, rowptr, elist, B2, N);

    // edge-MLP first layer, per-node halves: Pa = h2@Wm1_top (B0, bf16), Pb = h2@Wm1_bot (B1, bf16)
    gemm_dual_kernel<64><<<(N + 31) / 32, 256, 0, stream>>>(B2, Wm1, Wm1 + 64 * 64, B0h, B1h, N);

    // per-edge: out = relu(Pa[src] + Pb[dst] + bm1) @ Wm2 + bm2
    edge_out_kernel<<<E / 64, 256, 0, stream>>>(B0h, B1h, ei, bm1, Wm2, bm2, out, E);
}